// Round 6
// baseline (88.783 us; speedup 1.0000x reference)
//
#include <hip/hip_runtime.h>
#include <hip/hip_bf16.h>

#define BLOCK 256
#define GRID  2048                    // 8 blocks/CU x 256 CUs
#define N_ELEM 16777216               // B*C for this problem
#define PT_V4 (N_ELEM / 4 / (GRID * BLOCK))   // = 8 float4 per array per thread

// BCE-with-logits, masked row sum, product-of-factors form:
//   loss = max(x,0) + log(1+exp(-|x|)) - x*t
// log terms accumulate multiplicatively (one __logf per thread at the end).
__device__ __forceinline__ void bce4(const float4 xv, const float4 tv,
                                     float& sum_lin, float& prod) {
    const bool b0 = (tv.x + tv.y) > 0.0f;   // row mask (2 cols/row)
    const bool b1 = (tv.z + tv.w) > 0.0f;
    const float m0 = b0 ? 1.0f : 0.0f;
    const float m1 = b1 ? 1.0f : 0.0f;

    const float f0 = 1.0f + __expf(-fabsf(xv.x));
    const float f1 = 1.0f + __expf(-fabsf(xv.y));
    const float f2 = 1.0f + __expf(-fabsf(xv.z));
    const float f3 = 1.0f + __expf(-fabsf(xv.w));
    prod *= b0 ? (f0 * f1) : 1.0f;
    prod *= b1 ? (f2 * f3) : 1.0f;

    const float r0 = __builtin_fmaf(-xv.x, tv.x, fmaxf(xv.x, 0.0f));
    const float r1 = __builtin_fmaf(-xv.y, tv.y, fmaxf(xv.y, 0.0f));
    const float r2 = __builtin_fmaf(-xv.z, tv.z, fmaxf(xv.z, 0.0f));
    const float r3 = __builtin_fmaf(-xv.w, tv.w, fmaxf(xv.w, 0.0f));
    sum_lin = __builtin_fmaf(m0, r0 + r1, sum_lin);
    sum_lin = __builtin_fmaf(m1, r2 + r3, sum_lin);
}

// Single fused kernel: grid reduction finished by the last-arriving block.
// Counter is free-running mod GRID (GRID divides 2^32), so ANY initial
// counter value (incl. 0xAAAAAAAA poison) works — no memset dispatch needed,
// and behavior is identical on every replay.
__global__ __launch_bounds__(BLOCK) void bce_fused_kernel(
        const float4* __restrict__ x4,
        const float4* __restrict__ t4,
        float* __restrict__ partials,          // [GRID] in d_ws
        unsigned int* __restrict__ counter,    // 1 uint in d_ws
        float* __restrict__ out) {
    const int tid    = blockIdx.x * BLOCK + threadIdx.x;
    const int stride = GRID * BLOCK;

    // Issue all loads up-front for maximum memory-level parallelism.
    float4 xv[PT_V4], tv[PT_V4];
    #pragma unroll
    for (int k = 0; k < PT_V4; ++k) xv[k] = x4[tid + k * stride];
    #pragma unroll
    for (int k = 0; k < PT_V4; ++k) tv[k] = t4[tid + k * stride];

    float sum_lin = 0.0f, prod = 1.0f;
    #pragma unroll
    for (int k = 0; k < PT_V4; ++k) bce4(xv[k], tv[k], sum_lin, prod);
    float sum = sum_lin + __logf(prod);   // one log per thread

    #pragma unroll
    for (int off = 32; off > 0; off >>= 1)
        sum += __shfl_down(sum, off, 64);

    __shared__ float wsum[BLOCK / 64];
    __shared__ bool  last_block;
    const int lane = threadIdx.x & 63;
    const int wid  = threadIdx.x >> 6;
    if (lane == 0) wsum[wid] = sum;
    __syncthreads();

    if (threadIdx.x == 0) {
        float b = wsum[0] + wsum[1] + wsum[2] + wsum[3];
        partials[blockIdx.x] = b;
        __threadfence();                          // release partials (device scope)
        const unsigned int old = atomicAdd(counter, 1u);
        last_block = ((old & (GRID - 1)) == (GRID - 1));
    }
    __syncthreads();

    if (last_block) {                             // block-uniform branch
        __threadfence();                          // acquire other blocks' stores
        volatile const float* vp = partials;      // bypass L1 for cross-XCD reads
        double s = 0.0;
        #pragma unroll
        for (int k = 0; k < GRID / BLOCK; ++k)
            s += (double)vp[threadIdx.x + k * BLOCK];

        #pragma unroll
        for (int off = 32; off > 0; off >>= 1)
            s += __shfl_down(s, off, 64);

        __shared__ double dsum[BLOCK / 64];
        if (lane == 0) dsum[wid] = s;
        __syncthreads();
        if (threadIdx.x == 0) {
            const double b = dsum[0] + dsum[1] + dsum[2] + dsum[3];
            out[0] = (float)(b * (1.0 / (double)N_ELEM));
        }
    }
}

// ---- generic fallback (n != N_ELEM), two-kernel path from round 5 ----
__global__ __launch_bounds__(BLOCK) void bce_partial_generic(
        const float4* __restrict__ x4, const float4* __restrict__ t4,
        float* __restrict__ partials, int n4) {
    float sum_lin = 0.0f, prod = 1.0f;
    const int stride = gridDim.x * blockDim.x;
    for (int i = blockIdx.x * blockDim.x + threadIdx.x; i < n4; i += stride) {
        bce4(x4[i], t4[i], sum_lin, prod);
    }
    float sum = sum_lin + __logf(prod);
    #pragma unroll
    for (int off = 32; off > 0; off >>= 1) sum += __shfl_down(sum, off, 64);
    __shared__ float wsum[BLOCK / 64];
    const int lane = threadIdx.x & 63, wid = threadIdx.x >> 6;
    if (lane == 0) wsum[wid] = sum;
    __syncthreads();
    if (threadIdx.x == 0)
        partials[blockIdx.x] = wsum[0] + wsum[1] + wsum[2] + wsum[3];
}

__global__ __launch_bounds__(BLOCK) void bce_finalize_generic(
        const float* __restrict__ partials, float* __restrict__ out, double inv_n) {
    double s = 0.0;
    #pragma unroll
    for (int k = 0; k < GRID / BLOCK; ++k)
        s += (double)partials[threadIdx.x + k * BLOCK];
    #pragma unroll
    for (int off = 32; off > 0; off >>= 1) s += __shfl_down(s, off, 64);
    __shared__ double dsum[BLOCK / 64];
    const int lane = threadIdx.x & 63, wid = threadIdx.x >> 6;
    if (lane == 0) dsum[wid] = s;
    __syncthreads();
    if (threadIdx.x == 0)
        out[0] = (float)((dsum[0] + dsum[1] + dsum[2] + dsum[3]) * inv_n);
}

extern "C" void kernel_launch(void* const* d_in, const int* in_sizes, int n_in,
                              void* d_out, int out_size, void* d_ws, size_t ws_size,
                              hipStream_t stream) {
    const float* x = (const float*)d_in[0];   // inputs  [B,2] f32
    const float* t = (const float*)d_in[1];   // targets [B,2] f32
    float* out = (float*)d_out;
    float* partials = (float*)d_ws;                       // GRID * 4 B
    unsigned int* counter = (unsigned int*)((char*)d_ws + GRID * sizeof(float));

    const int n = in_sizes[0];

    if (n == N_ELEM) {
        bce_fused_kernel<<<GRID, BLOCK, 0, stream>>>(
            (const float4*)x, (const float4*)t, partials, counter, out);
    } else {
        const int n4 = n / 4;
        bce_partial_generic<<<GRID, BLOCK, 0, stream>>>(
            (const float4*)x, (const float4*)t, partials, n4);
        bce_finalize_generic<<<1, BLOCK, 0, stream>>>(partials, out, 1.0 / (double)n);
    }
}

// Round 8
// 31.535 us; speedup vs baseline: 2.8154x; 2.8154x over previous
//
#include <hip/hip_runtime.h>
#include <hip/hip_bf16.h>

#define BLOCK 256
#define GRID  2048                  // 8 blocks/CU x 256 CUs
#define N_ELEM 16777216             // B*C for this problem
#define N4_FIX (N_ELEM / 4)         // 4194304 float4 per array
#define PT_V4 (N4_FIX / (GRID * BLOCK))   // 8 float4 per array per thread

// BCE-with-logits, masked row sum, product-of-factors form:
//   loss = max(x,0) + log(1+exp(-|x|)) - x*t
// log terms accumulate multiplicatively -> one __logf per thread at the end.
// 32 elems/thread, factors in (1,2] -> prod <= 2^32, safe in f32.
__device__ __forceinline__ void bce4(const float4 xv, const float4 tv,
                                     float& sum_lin, float& prod) {
    const bool b0 = (tv.x + tv.y) > 0.0f;   // row mask (2 cols/row)
    const bool b1 = (tv.z + tv.w) > 0.0f;
    const float m0 = b0 ? 1.0f : 0.0f;
    const float m1 = b1 ? 1.0f : 0.0f;

    const float f0 = 1.0f + __expf(-fabsf(xv.x));
    const float f1 = 1.0f + __expf(-fabsf(xv.y));
    const float f2 = 1.0f + __expf(-fabsf(xv.z));
    const float f3 = 1.0f + __expf(-fabsf(xv.w));
    prod *= b0 ? (f0 * f1) : 1.0f;
    prod *= b1 ? (f2 * f3) : 1.0f;

    const float r0 = __builtin_fmaf(-xv.x, tv.x, fmaxf(xv.x, 0.0f));
    const float r1 = __builtin_fmaf(-xv.y, tv.y, fmaxf(xv.y, 0.0f));
    const float r2 = __builtin_fmaf(-xv.z, tv.z, fmaxf(xv.z, 0.0f));
    const float r3 = __builtin_fmaf(-xv.w, tv.w, fmaxf(xv.w, 0.0f));
    sum_lin = __builtin_fmaf(m0, r0 + r1, sum_lin);
    sum_lin = __builtin_fmaf(m1, r2 + r3, sum_lin);
}

// Specialized partial kernel: N known at compile time -> all 16 float4 loads
// issued up-front (max memory-level parallelism), zero bounds checks.
__global__ __launch_bounds__(BLOCK) void bce_partial_fix(
        const float4* __restrict__ x4,
        const float4* __restrict__ t4,
        float* __restrict__ partials) {
    const int tid = blockIdx.x * BLOCK + threadIdx.x;
    const int stride = GRID * BLOCK;

    float4 xv[PT_V4], tv[PT_V4];
    #pragma unroll
    for (int k = 0; k < PT_V4; ++k) xv[k] = x4[tid + k * stride];
    #pragma unroll
    for (int k = 0; k < PT_V4; ++k) tv[k] = t4[tid + k * stride];

    float sum_lin = 0.0f, prod = 1.0f;
    #pragma unroll
    for (int k = 0; k < PT_V4; ++k) bce4(xv[k], tv[k], sum_lin, prod);
    float sum = sum_lin + __logf(prod);   // one log per thread

    #pragma unroll
    for (int off = 32; off > 0; off >>= 1)
        sum += __shfl_down(sum, off, 64);

    __shared__ float wsum[BLOCK / 64];
    const int lane = threadIdx.x & 63;
    const int wid  = threadIdx.x >> 6;
    if (lane == 0) wsum[wid] = sum;
    __syncthreads();

    if (threadIdx.x == 0)
        partials[blockIdx.x] = wsum[0] + wsum[1] + wsum[2] + wsum[3];
}

// Generic fallback (any n divisible by 4) — round-5 verified code.
__global__ __launch_bounds__(BLOCK) void bce_partial_generic(
        const float4* __restrict__ x4, const float4* __restrict__ t4,
        float* __restrict__ partials, int n4) {
    float sum_lin = 0.0f, prod = 1.0f;
    const int stride = gridDim.x * blockDim.x;
    for (int i = blockIdx.x * blockDim.x + threadIdx.x; i < n4; i += 2 * stride) {
        bce4(x4[i], t4[i], sum_lin, prod);
        const int j = i + stride;
        if (j < n4) bce4(x4[j], t4[j], sum_lin, prod);
    }
    float sum = sum_lin + __logf(prod);
    #pragma unroll
    for (int off = 32; off > 0; off >>= 1) sum += __shfl_down(sum, off, 64);
    __shared__ float wsum[BLOCK / 64];
    const int lane = threadIdx.x & 63, wid = threadIdx.x >> 6;
    if (lane == 0) wsum[wid] = sum;
    __syncthreads();
    if (threadIdx.x == 0)
        partials[blockIdx.x] = wsum[0] + wsum[1] + wsum[2] + wsum[3];
}

__global__ __launch_bounds__(BLOCK) void bce_finalize(
        const float* __restrict__ partials, float* __restrict__ out, double inv_n) {
    double s = 0.0;
    #pragma unroll
    for (int k = 0; k < GRID / BLOCK; ++k)
        s += (double)partials[threadIdx.x + k * BLOCK];
    #pragma unroll
    for (int off = 32; off > 0; off >>= 1) s += __shfl_down(s, off, 64);
    __shared__ double dsum[BLOCK / 64];
    const int lane = threadIdx.x & 63, wid = threadIdx.x >> 6;
    if (lane == 0) dsum[wid] = s;
    __syncthreads();
    if (threadIdx.x == 0)
        out[0] = (float)((dsum[0] + dsum[1] + dsum[2] + dsum[3]) * inv_n);
}

extern "C" void kernel_launch(void* const* d_in, const int* in_sizes, int n_in,
                              void* d_out, int out_size, void* d_ws, size_t ws_size,
                              hipStream_t stream) {
    const float* x = (const float*)d_in[0];   // inputs  [B,2] f32
    const float* t = (const float*)d_in[1];   // targets [B,2] f32
    float* out = (float*)d_out;
    float* partials = (float*)d_ws;           // 8 KB scratch

    const int n = in_sizes[0];

    if (n == N_ELEM) {
        bce_partial_fix<<<GRID, BLOCK, 0, stream>>>(
            (const float4*)x, (const float4*)t, partials);
    } else {
        bce_partial_generic<<<GRID, BLOCK, 0, stream>>>(
            (const float4*)x, (const float4*)t, partials, n / 4);
    }
    bce_finalize<<<1, BLOCK, 0, stream>>>(partials, out, 1.0 / (double)n);
}

// Round 9
// 27.676 us; speedup vs baseline: 3.2080x; 1.1394x over previous
//
#include <hip/hip_runtime.h>
#include <hip/hip_bf16.h>

#define BLOCK 256
#define GRID  2048   // 8 blocks/CU x 256 CUs, whole grid co-resident

// BCE-with-logits, masked row sum, product-of-factors form:
//   loss = max(x,0) + log(1+exp(-|x|)) - x*t
// log terms accumulate multiplicatively -> one __logf per thread at the end.
// 32 elems/thread, factors in (1,2] -> prod <= 2^32, safe in f32;
// log abs-error ~2e-6, far below the 1.2e-2 threshold.
__device__ __forceinline__ void bce4(const float4 xv, const float4 tv,
                                     float& sum_lin, float& prod) {
    const bool b0 = (tv.x + tv.y) > 0.0f;   // row mask (2 cols/row)
    const bool b1 = (tv.z + tv.w) > 0.0f;
    const float m0 = b0 ? 1.0f : 0.0f;
    const float m1 = b1 ? 1.0f : 0.0f;

    const float f0 = 1.0f + __expf(-fabsf(xv.x));
    const float f1 = 1.0f + __expf(-fabsf(xv.y));
    const float f2 = 1.0f + __expf(-fabsf(xv.z));
    const float f3 = 1.0f + __expf(-fabsf(xv.w));
    prod *= b0 ? (f0 * f1) : 1.0f;
    prod *= b1 ? (f2 * f3) : 1.0f;

    const float r0 = __builtin_fmaf(-xv.x, tv.x, fmaxf(xv.x, 0.0f));
    const float r1 = __builtin_fmaf(-xv.y, tv.y, fmaxf(xv.y, 0.0f));
    const float r2 = __builtin_fmaf(-xv.z, tv.z, fmaxf(xv.z, 0.0f));
    const float r3 = __builtin_fmaf(-xv.w, tv.w, fmaxf(xv.w, 0.0f));
    sum_lin = __builtin_fmaf(m0, r0 + r1, sum_lin);
    sum_lin = __builtin_fmaf(m1, r2 + r3, sum_lin);
}

// Round-5 verified partial kernel (28.1 us total): grid-stride loop,
// 2 float4-pairs per iteration, plain per-block store (no atomics).
__global__ __launch_bounds__(BLOCK) void bce_partial_kernel(
        const float4* __restrict__ x4,
        const float4* __restrict__ t4,
        float* __restrict__ partials,
        int n4) {
    float sum_lin = 0.0f, prod = 1.0f;
    const int stride = gridDim.x * blockDim.x;
    for (int i = blockIdx.x * blockDim.x + threadIdx.x; i < n4; i += 2 * stride) {
        bce4(x4[i], t4[i], sum_lin, prod);
        const int j = i + stride;
        if (j < n4) bce4(x4[j], t4[j], sum_lin, prod);
    }
    float sum = sum_lin + __logf(prod);   // one log per thread

    #pragma unroll
    for (int off = 32; off > 0; off >>= 1)
        sum += __shfl_down(sum, off, 64);

    __shared__ float wsum[BLOCK / 64];
    const int lane = threadIdx.x & 63;
    const int wid  = threadIdx.x >> 6;
    if (lane == 0) wsum[wid] = sum;
    __syncthreads();

    if (threadIdx.x == 0)
        partials[blockIdx.x] = wsum[0] + wsum[1] + wsum[2] + wsum[3];
}

// Single-wave finalize: 64 threads, no LDS, no barriers, float4 loads.
// Reads GRID=2048 partials (8 float4 per thread), double accumulate.
__global__ __launch_bounds__(64) void bce_finalize_kernel(
        const float4* __restrict__ partials4,
        float* __restrict__ out,
        double inv_n) {
    double s = 0.0;
    #pragma unroll
    for (int k = 0; k < GRID / 4 / 64; ++k) {          // 8 float4 per thread
        const float4 v = partials4[threadIdx.x + k * 64];
        s += (double)v.x + (double)v.y + (double)v.z + (double)v.w;
    }
    #pragma unroll
    for (int off = 32; off > 0; off >>= 1)
        s += __shfl_down(s, off, 64);

    if (threadIdx.x == 0)
        out[0] = (float)(s * inv_n);
}

extern "C" void kernel_launch(void* const* d_in, const int* in_sizes, int n_in,
                              void* d_out, int out_size, void* d_ws, size_t ws_size,
                              hipStream_t stream) {
    const float* x = (const float*)d_in[0];   // inputs  [B,2] f32
    const float* t = (const float*)d_in[1];   // targets [B,2] f32
    float* out = (float*)d_out;
    float* partials = (float*)d_ws;           // 8 KB scratch

    const int n  = in_sizes[0];   // B*C = 16777216, divisible by 4
    const int n4 = n / 4;

    bce_partial_kernel<<<GRID, BLOCK, 0, stream>>>(
        (const float4*)x, (const float4*)t, partials, n4);

    bce_finalize_kernel<<<1, 64, 0, stream>>>(
        (const float4*)partials, out, 1.0 / (double)n);
}